// Round 2
// baseline (184.225 us; speedup 1.0000x reference)
//
#include <hip/hip_runtime.h>
#include <hip/hip_bf16.h>

typedef __hip_bfloat16 bf16;
typedef __attribute__((ext_vector_type(8))) short  bfrag;   // 8 bf16 (4 VGPR) MFMA A/B frag
typedef __attribute__((ext_vector_type(4))) float  facc;    // MFMA C/D frag
typedef __attribute__((ext_vector_type(4))) short  short4v; // 4 bf16 = 8B packed store

#define B_   8
#define T_   1024
#define C_   768
#define H_   12
#define HD_  64
#define M_   (B_ * T_)   // 8192
#define N3_  (3 * C_)    // 2304

// Q is stored pre-scaled by 0.125*log2(e) so flash softmax is p = exp2(s - M2)
#define QSCALE_ 0.18033688011112042f
#define M2_     17.312340490667562f

__device__ __forceinline__ float fexp2(float x) { return __builtin_amdgcn_exp2f(x); }

__device__ __forceinline__ void gload_lds16(const bf16* g, bf16* l) {
    __builtin_amdgcn_global_load_lds((const __attribute__((address_space(1))) void*)g,
                                     (__attribute__((address_space(3))) void*)l, 16, 0, 0);
}
__device__ __forceinline__ short bfbits(float f) {
    bf16 b = __float2bfloat16(f);
    return *reinterpret_cast<short*>(&b);
}

// ---------- fused converts: x->bf16, W_attn->bf16^T, W_proj->bf16^T ----------
#define XBLK 6144                       // x: 6291456 / (256*4)
#define WABLK 1728                      // (2304/32)*(768/32)
__global__ __launch_bounds__(256) void cvt_all_kernel(
        const float* __restrict__ x,  bf16* __restrict__ xb,
        const float* __restrict__ wa, bf16* __restrict__ wat,
        const float* __restrict__ wp, bf16* __restrict__ wpt) {
    const int bid = blockIdx.x, t = threadIdx.x;
    if (bid < XBLK) {
        const size_t i = ((size_t)bid * 256 + t) * 4;
        const float4 v = *(const float4*)(x + i);
        bf16* o = xb + i;
        o[0] = __float2bfloat16(v.x); o[1] = __float2bfloat16(v.y);
        o[2] = __float2bfloat16(v.z); o[3] = __float2bfloat16(v.w);
        return;
    }
    __shared__ float tile[32][33];
    const float* w; bf16* wt; int N, tI;
    if (bid < XBLK + WABLK) { w = wa; wt = wat; N = N3_; tI = bid - XBLK; }
    else                    { w = wp; wt = wpt; N = C_;  tI = bid - XBLK - WABLK; }
    const int ntn = N / 32;
    const int n0 = (tI % ntn) * 32, k0 = (tI / ntn) * 32;
    const int tx = t & 31, ty = t >> 5;        // 32 x 8
    for (int i = ty; i < 32; i += 8) tile[i][tx] = w[(size_t)(k0 + i) * N + n0 + tx];
    __syncthreads();
    for (int i = ty; i < 32; i += 8)
        wt[(size_t)(n0 + i) * C_ + k0 + tx] = __float2bfloat16(tile[tx][i]);
}

// ---------- 8-wave pipelined MFMA GEMM core: BM=MI*64, BN=192, BK=64 ----------
// 512 threads = 8 waves (4 row-waves x 2 col-waves), wave tile (MI*16)x96.
// LDS: A dbuf 2x[BM*64], B dbuf 2x[192*64], XOR chunk-swizzled. 1 block/CU,
// 2 waves/SIMD so phase stagger overlaps MFMA with ds_read/lgkm across waves.
// 3 phases per K-tile; counted vmcnt (never 0 in steady state):
//  per-thread loads/tile: A=LA(=MI), B=3 (units B0,B1,B2 of 64 rows each).
//  consumption: ph0 needs A,B0,B1(t); ph1+ needs B2(t).
//  ph0: issue A(t+1), vmcnt(LA)  -> completes B2(t)
//  ph1: issue B(t+1)  (no wait)
//  ph2: vmcnt(1)                 -> completes A,B0,B1(t+1); B2(t+1) in flight

#define WAIT_VM(N) asm volatile("s_waitcnt vmcnt(" #N ")" ::: "memory")
#define PHASE_MID() do { __builtin_amdgcn_s_barrier();                 \
    asm volatile("s_waitcnt lgkmcnt(0)" ::: "memory");                 \
    __builtin_amdgcn_sched_barrier(0);                                 \
    __builtin_amdgcn_s_setprio(1); } while (0)
#define PHASE_END() do { __builtin_amdgcn_s_setprio(0);                \
    __builtin_amdgcn_s_barrier(); } while (0)

#define L_A() _Pragma("unroll") for (int i = 0; i < MI; ++i) {                 \
    const bf16* ar = AsC + (wrow + i * 16 + fr) * 64;                          \
    af[i][0] = *(const bfrag*)(ar + pc0);                                      \
    af[i][1] = *(const bfrag*)(ar + pc1); }

#define L_B(P) _Pragma("unroll") for (int j = 0; j < 2; ++j) {                 \
    const bf16* br = BsC + (wcol + ((P) * 2 + j) * 16 + fr) * 64;              \
    bf_[j][0] = *(const bfrag*)(br + pc0);                                     \
    bf_[j][1] = *(const bfrag*)(br + pc1); }

#define MM(P) _Pragma("unroll") for (int i = 0; i < MI; ++i)                   \
    _Pragma("unroll") for (int j = 0; j < 2; ++j) {                            \
      facc& a = acc[i][(P) * 2 + j];                                           \
      if constexpr (SWAPPED) {                                                 \
        a = __builtin_amdgcn_mfma_f32_16x16x32_bf16(bf_[j][0], af[i][0], a, 0, 0, 0); \
        a = __builtin_amdgcn_mfma_f32_16x16x32_bf16(bf_[j][1], af[i][1], a, 0, 0, 0); \
      } else {                                                                 \
        a = __builtin_amdgcn_mfma_f32_16x16x32_bf16(af[i][0], bf_[j][0], a, 0, 0, 0); \
        a = __builtin_amdgcn_mfma_f32_16x16x32_bf16(af[i][1], bf_[j][1], a, 0, 0, 0); \
      } }

template<int MI, bool SWAPPED>
__device__ __forceinline__ void gemm8w_core(
        const bf16* __restrict__ Ap, const bf16* __restrict__ Bp,
        const int m0, const int n0, bf16* smem, facc (&acc)[MI][6]) {
    constexpr int KD = 768, NT = 12;
    constexpr int BM  = MI * 64;          // 256 or 128
    constexpr int LA  = MI;               // A gloads/thread/tile (4 or 2)
    constexpr int ASZ = BM * 64;          // elems per A buffer
    bf16* As = smem;                      // [2][ASZ]
    bf16* Bs = smem + 2 * ASZ;            // [2][12288]
    const int t = threadIdx.x, w = t >> 6, lane = t & 63;
    const int wrow = (w >> 1) * (MI * 16);           // 4 row-waves
    const int wcol = (w & 1) * 96;                   // 2 col-waves
    const int fr = lane & 15, quad = lane >> 4;
    const int pc0 = (quad ^ (fr & 7)) * 8;           // swizzled read chunk, kk=0
    const int pc1 = ((quad + 4) ^ (fr & 7)) * 8;     // kk=1
    const int srow = t >> 3;                         // 0..63 staging row
    const int schunk = ((t & 7) ^ (srow & 7)) * 8;   // swizzled source chunk
    const int sdo = t * 8;                           // linear LDS dest

    const bf16* Ag = Ap + (size_t)(m0 + srow) * KD + schunk;
    const bf16* Bg = Bp + (size_t)(n0 + srow) * KD + schunk;

#pragma unroll
    for (int i = 0; i < MI; ++i)
#pragma unroll
        for (int c = 0; c < 6; ++c)
#pragma unroll
            for (int r = 0; r < 4; ++r) acc[i][c][r] = 0.f;

    auto stageA = [&](bf16* dst, int k0) {           // LA passes of 64 rows
        const bf16* s = Ag + k0;
        bf16* d = dst + sdo;
#pragma unroll
        for (int r = 0; r < LA; ++r)
            gload_lds16(s + (size_t)(r * 64) * KD, d + r * 4096);
    };
    auto stageB = [&](bf16* dst, int k0) {           // 3 passes of 64 rows
        const bf16* s = Bg + k0;
        bf16* d = dst + sdo;
#pragma unroll
        for (int r = 0; r < 3; ++r)
            gload_lds16(s + (size_t)(r * 64) * KD, d + r * 4096);
    };

    // prologue: stage tile 0 fully
    stageA(As, 0);
    stageB(Bs, 0);
    WAIT_VM(0);
    __builtin_amdgcn_s_barrier();

#pragma unroll 2
    for (int kt = 0; kt < NT; ++kt) {
        const int cb = kt & 1;
        const bf16* AsC = As + cb * ASZ;
        const bf16* BsC = Bs + cb * 12288;
        bf16* AsN = As + (cb ^ 1) * ASZ;
        bf16* BsN = Bs + (cb ^ 1) * 12288;
        const int kn = (kt + 1) * 64;
        const bool nl = kt + 1 < NT;
        bfrag af[MI][2], bf_[2][2];

        // phase 0: consume A(t)+B cols 0-1; prefetch A(t+1)
        L_A();
        L_B(0);
        if (nl) {
            stageA(AsN, kn);
            if constexpr (MI == 4) WAIT_VM(4); else WAIT_VM(2);
        } else {
            WAIT_VM(0);
        }
        PHASE_MID();
        MM(0);
        PHASE_END();

        // phase 1: consume B cols 2-3; prefetch B(t+1)
        L_B(1);
        if (nl) stageB(BsN, kn);
        PHASE_MID();
        MM(1);
        PHASE_END();

        // phase 2: consume B cols 4-5; wait A,B0,B1(t+1) (B2 stays in flight)
        L_B(2);
        if (nl) WAIT_VM(1);
        PHASE_MID();
        MM(2);
        PHASE_END();
    }
}

// qkv: A=xb [8192x768], Bt=WaT [2304x768] -> Q,K [B,H,T,64] bf16 (swapped, packed),
// V transposed Vt [B,H,64,T] (non-swapped). Grid 384 blocks (1.5/CU), 512 thr.
__global__ __launch_bounds__(512, 2) void qkv8_kernel(
        const bf16* __restrict__ xb, const bf16* __restrict__ wat,
        const float* __restrict__ bias,
        bf16* __restrict__ Q, bf16* __restrict__ K, bf16* __restrict__ Vt) {
    extern __shared__ bf16 smem[];
    const int id = blockIdx.x;
    const int wg = (id & 7) * 48 + (id >> 3);      // bijective XCD swizzle (384%8==0)
    const int bx = wg % 12, by = wg / 12;
    const int m0 = by * 256, n0 = bx * 192;
    const int which = n0 / C_;                     // block-uniform: 0=Q 1=K 2=V

    facc acc[4][6];
    if (which < 2) gemm8w_core<4, true >(xb, wat, m0, n0, smem, acc);
    else           gemm8w_core<4, false>(xb, wat, m0, n0, smem, acc);

    const int t = threadIdx.x, w = t >> 6, lane = t & 63;
    const int wr = (w >> 1) * 64, wc = (w & 1) * 96;
    const int fr = lane & 15, quad = lane >> 4;
    const int bb = m0 >> 10;                       // uniform batch index
    if (which < 2) {
        bf16* dst = which ? K : Q;
        const float sc = which ? 1.0f : QSCALE_;
#pragma unroll
        for (int i = 0; i < 4; ++i) {
            const int tt = (m0 & 1023) + wr + i * 16 + fr;     // token (lane-major)
#pragma unroll
            for (int c = 0; c < 6; ++c) {
                const int colbase = n0 + wc + c * 16 + quad * 4;
                const int cc = colbase - which * C_;
                const int h = cc >> 6, d0 = cc & 63;
                const float4 bv = *(const float4*)(bias + colbase);
                short4v pk;
                pk[0] = bfbits((acc[i][c][0] + bv.x) * sc);
                pk[1] = bfbits((acc[i][c][1] + bv.y) * sc);
                pk[2] = bfbits((acc[i][c][2] + bv.z) * sc);
                pk[3] = bfbits((acc[i][c][3] + bv.w) * sc);
                *(short4v*)(dst + ((size_t)(bb * H_ + h) * T_ + tt) * HD_ + d0) = pk;
            }
        }
    } else {
#pragma unroll
        for (int i = 0; i < 4; ++i) {
            const int tt0 = (m0 & 1023) + wr + i * 16 + quad * 4;  // token, +r over pack
#pragma unroll
            for (int c = 0; c < 6; ++c) {
                const int col = n0 + wc + c * 16 + fr;
                const int cc = col - 2 * C_;
                const int h = cc >> 6, d = cc & 63;
                const float bv = bias[col];
                short4v pk;
                pk[0] = bfbits(acc[i][c][0] + bv);
                pk[1] = bfbits(acc[i][c][1] + bv);
                pk[2] = bfbits(acc[i][c][2] + bv);
                pk[3] = bfbits(acc[i][c][3] + bv);
                *(short4v*)(Vt + ((size_t)(bb * H_ + h) * HD_ + d) * T_ + tt0) = pk;
            }
        }
    }
}

// proj: A=Y [8192x768] bf16, Bt=WpT [768x768] -> fp32 out + bias (swapped).
// Grid 256 blocks = exactly 1/CU, 512 thr, MI=2 (BM=128).
__global__ __launch_bounds__(512, 2) void proj8_kernel(
        const bf16* __restrict__ y, const bf16* __restrict__ wpt,
        const float* __restrict__ bias, float* __restrict__ out) {
    extern __shared__ bf16 smem[];
    const int id = blockIdx.x;
    const int wg = (id & 7) * 32 + (id >> 3);      // bijective XCD swizzle (256%8==0)
    const int bx = wg % 4, by = wg / 4;
    const int m0 = by * 128, n0 = bx * 192;

    facc acc[2][6];
    gemm8w_core<2, true>(y, wpt, m0, n0, smem, acc);

    const int t = threadIdx.x, w = t >> 6, lane = t & 63;
    const int wr = (w >> 1) * 32, wc = (w & 1) * 96;
    const int fr = lane & 15, quad = lane >> 4;
#pragma unroll
    for (int i = 0; i < 2; ++i) {
        const int row = m0 + wr + i * 16 + fr;
#pragma unroll
        for (int c = 0; c < 6; ++c) {
            const int colbase = n0 + wc + c * 16 + quad * 4;
            const float4 bv = *(const float4*)(bias + colbase);
            float4 v;
            v.x = acc[i][c][0] + bv.x;
            v.y = acc[i][c][1] + bv.y;
            v.z = acc[i][c][2] + bv.z;
            v.w = acc[i][c][3] + bv.w;
            *(float4*)(out + (size_t)row * C_ + colbase) = v;
        }
    }
}

// ---------- flash attention: exp2 static-max softmax + 2 K-tiles per barrier ----------
__global__ __launch_bounds__(256) void flash_attn_kernel(
        const bf16* __restrict__ Q, const bf16* __restrict__ K,
        const bf16* __restrict__ Vt, bf16* __restrict__ Y) {
    const int id   = blockIdx.x;
    const int bh   = (id & 7) * 12 + ((id >> 3) % 12);    // XCD affinity
    const int qpair = (id >> 3) / 12;                     // 0..7
    const int t = threadIdx.x, w = t >> 6, lane = t & 63;
    const int fr = lane & 15, quad = lane >> 4, fq = quad * 8;

    __shared__ bf16 sK[2][64 * 64];       // [buf][key][dim], chunk-swizzled
    __shared__ bf16 sVt[2][64 * 64];      // [buf][dim][key], chunk-swizzled
    __shared__ bf16 sP[4][16][72];        // wave-private P, row stride 72 (16B aligned)

    const bf16* Kbh = K  + (size_t)bh * T_ * HD_;
    const bf16* Vbh = Vt + (size_t)bh * HD_ * T_;
    const int b_ = bh / H_, h_ = bh % H_;

    const int srow = t >> 3;                                // 0..31 (staging row)
    const int sgc  = ((t & 7) ^ (srow & 7)) * 8;            // swizzled source chunk
    const int c0   = (quad ^ (fr & 7)) * 8;                 // swizzled read chunk

    for (int phase = 0; phase < 2; ++phase) {
        const int qt = (phase == 0) ? (15 - qpair) : qpair; // heavy tile first
        const int q0 = qt * 64;

        const bf16* qbase = Q + ((size_t)bh * T_ + q0 + w * 16 + fr) * HD_;
        bfrag qa0 = *(const bfrag*)(qbase + fq);
        bfrag qa1 = *(const bfrag*)(qbase + 32 + fq);

        facc o[4];
        for (int nb = 0; nb < 4; ++nb) for (int r = 0; r < 4; ++r) o[nb][r] = 0.f;
        float rowl[4] = {0.f, 0.f, 0.f, 0.f};

        auto tile_step = [&](int kt, const bf16* sKp, const bf16* sVp) {
            const int k0 = kt * 64;
            facc s[4];
            for (int nb = 0; nb < 4; ++nb) for (int r = 0; r < 4; ++r) s[nb][r] = 0.f;
            for (int nb = 0; nb < 4; ++nb) {
                const bf16* kr = sKp + (nb * 16 + fr) * 64;
                bfrag kb0 = *(const bfrag*)(kr + c0);
                bfrag kb1 = *(const bfrag*)(kr + (c0 ^ 32));
                s[nb] = __builtin_amdgcn_mfma_f32_16x16x32_bf16(qa0, kb0, s[nb], 0, 0, 0);
                s[nb] = __builtin_amdgcn_mfma_f32_16x16x32_bf16(qa1, kb1, s[nb], 0, 0, 0);
            }
            const int mrow0 = q0 + w * 16 + quad * 4;   // + r
            float p[4][4];
            if (kt == qt) {
                for (int nb = 0; nb < 4; ++nb) {
                    const int n_g = k0 + nb * 16 + fr;
                    for (int r = 0; r < 4; ++r) {
                        const float a = (n_g > mrow0 + r) ? -1e30f : s[nb][r] - M2_;
                        p[nb][r] = fexp2(a);
                    }
                }
            } else {
                for (int nb = 0; nb < 4; ++nb)
                    for (int r = 0; r < 4; ++r)
                        p[nb][r] = fexp2(s[nb][r] - M2_);
            }
            for (int r = 0; r < 4; ++r)
                rowl[r] += p[0][r] + p[1][r] + p[2][r] + p[3][r];
            for (int nb = 0; nb < 4; ++nb)
                for (int r = 0; r < 4; ++r)
                    sP[w][quad * 4 + r][nb * 16 + fr] = __float2bfloat16(p[nb][r]);
            bfrag pa0 = *(const bfrag*)(&sP[w][fr][fq]);
            bfrag pa1 = *(const bfrag*)(&sP[w][fr][32 + fq]);
            for (int nb = 0; nb < 4; ++nb) {
                const bf16* vr = sVp + (nb * 16 + fr) * 64;
                bfrag vb0 = *(const bfrag*)(vr + c0);
                bfrag vb1 = *(const bfrag*)(vr + (c0 ^ 32));
                o[nb] = __builtin_amdgcn_mfma_f32_16x16x32_bf16(pa0, vb0, o[nb], 0, 0, 0);
                o[nb] = __builtin_amdgcn_mfma_f32_16x16x32_bf16(pa1, vb1, o[nb], 0, 0, 0);
            }
        };

        for (int kt = 0; kt <= qt; kt += 2) {
            const int k0 = kt * 64;
            const bool two = (kt + 1 <= qt);
            gload_lds16(Kbh + (size_t)(k0 + srow) * HD_ + sgc,      sK[0] + t * 8);
            gload_lds16(Kbh + (size_t)(k0 + 32 + srow) * HD_ + sgc, sK[0] + 2048 + t * 8);
            gload_lds16(Vbh + (size_t)srow * T_ + k0 + sgc,         sVt[0] + t * 8);
            gload_lds16(Vbh + (size_t)(srow + 32) * T_ + k0 + sgc,  sVt[0] + 2048 + t * 8);
            if (two) {
                const int k1 = k0 + 64;
                gload_lds16(Kbh + (size_t)(k1 + srow) * HD_ + sgc,      sK[1] + t * 8);
                gload_lds16(Kbh + (size_t)(k1 + 32 + srow) * HD_ + sgc, sK[1] + 2048 + t * 8);
                gload_lds16(Vbh + (size_t)srow * T_ + k1 + sgc,         sVt[1] + t * 8);
                gload_lds16(Vbh + (size_t)(srow + 32) * T_ + k1 + sgc,  sVt[1] + 2048 + t * 8);
            }
            __syncthreads();
            tile_step(kt, sK[0], sVt[0]);
            if (two) tile_step(kt + 1, sK[1], sVt[1]);
            __syncthreads();
        }

        for (int r = 0; r < 4; ++r) {
            float l = rowl[r];
            l += __shfl_xor(l, 1);
            l += __shfl_xor(l, 2);
            l += __shfl_xor(l, 4);
            l += __shfl_xor(l, 8);
            const float inv = 1.0f / l;
            const int tt = q0 + w * 16 + quad * 4 + r;
            bf16* yrow = Y + ((size_t)b_ * T_ + tt) * C_ + h_ * HD_;
            for (int nb = 0; nb < 4; ++nb)
                yrow[nb * 16 + fr] = __float2bfloat16(o[nb][r] * inv);
        }
    }
}

extern "C" void kernel_launch(void* const* d_in, const int* in_sizes, int n_in,
                              void* d_out, int out_size, void* d_ws, size_t ws_size,
                              hipStream_t stream) {
    const float* x      = (const float*)d_in[0];
    const float* W_attn = (const float*)d_in[1];
    const float* b_attn = (const float*)d_in[2];
    const float* W_proj = (const float*)d_in[3];
    const float* b_proj = (const float*)d_in[4];
    float* out = (float*)d_out;

    const size_t per = (size_t)B_ * H_ * T_ * HD_;   // 6291456 bf16
    bf16* Q   = (bf16*)d_ws;
    bf16* K   = Q + per;
    bf16* Vt  = K + per;                 // transposed V [B,H,64,T]
    bf16* XbY = Vt + per;                // x-bf16, later attention output Y
    bf16* WaT = XbY + per;
    bf16* WpT = WaT + (size_t)N3_ * C_;

    static bool s_attr = false;
    if (!s_attr) {
        hipFuncSetAttribute((const void*)qkv8_kernel,
                            hipFuncAttributeMaxDynamicSharedMemorySize, 114688);
        hipFuncSetAttribute((const void*)proj8_kernel,
                            hipFuncAttributeMaxDynamicSharedMemorySize, 81920);
        s_attr = true;
    }

    cvt_all_kernel<<<dim3(XBLK + WABLK + 576), dim3(256), 0, stream>>>(
        x, XbY, W_attn, WaT, W_proj, WpT);
    qkv8_kernel<<<dim3(384), dim3(512), 114688, stream>>>(
        XbY, WaT, b_attn, Q, K, Vt);
    flash_attn_kernel<<<dim3(768), dim3(256), 0, stream>>>(Q, K, Vt, XbY);
    proj8_kernel<<<dim3(256), dim3(512), 81920, stream>>>(
        XbY, WpT, b_proj, out);
}

// Round 3
// 175.786 us; speedup vs baseline: 1.0480x; 1.0480x over previous
//
#include <hip/hip_runtime.h>
#include <hip/hip_bf16.h>

typedef __hip_bfloat16 bf16;
typedef __attribute__((ext_vector_type(8))) short  bfrag;   // 8 bf16 (4 VGPR) MFMA A/B frag
typedef __attribute__((ext_vector_type(4))) float  facc;    // MFMA C/D frag
typedef __attribute__((ext_vector_type(4))) short  short4v; // 4 bf16 = 8B packed store

#define B_   8
#define T_   1024
#define C_   768
#define H_   12
#define HD_  64
#define M_   (B_ * T_)   // 8192
#define N3_  (3 * C_)    // 2304

// Q is stored pre-scaled by 0.125*log2(e) so flash softmax is p = exp2(s - M2)
#define QSCALE_ 0.18033688011112042f
#define M2_     17.312340490667562f

__device__ __forceinline__ float fexp2(float x) { return __builtin_amdgcn_exp2f(x); }

__device__ __forceinline__ void gload_lds16(const bf16* g, bf16* l) {
    __builtin_amdgcn_global_load_lds((const __attribute__((address_space(1))) void*)g,
                                     (__attribute__((address_space(3))) void*)l, 16, 0, 0);
}
__device__ __forceinline__ short bfbits(float f) {
    bf16 b = __float2bfloat16(f);
    return *reinterpret_cast<short*>(&b);
}

// ---------- fused converts: x->bf16, W_attn->bf16^T, W_proj->bf16^T ----------
#define XBLK 6144                       // x: 6291456 / (256*4)
#define WABLK 1728                      // (2304/32)*(768/32)
__global__ __launch_bounds__(256) void cvt_all_kernel(
        const float* __restrict__ x,  bf16* __restrict__ xb,
        const float* __restrict__ wa, bf16* __restrict__ wat,
        const float* __restrict__ wp, bf16* __restrict__ wpt) {
    const int bid = blockIdx.x, t = threadIdx.x;
    if (bid < XBLK) {
        const size_t i = ((size_t)bid * 256 + t) * 4;
        const float4 v = *(const float4*)(x + i);
        bf16* o = xb + i;
        o[0] = __float2bfloat16(v.x); o[1] = __float2bfloat16(v.y);
        o[2] = __float2bfloat16(v.z); o[3] = __float2bfloat16(v.w);
        return;
    }
    __shared__ float tile[32][33];
    const float* w; bf16* wt; int N, tI;
    if (bid < XBLK + WABLK) { w = wa; wt = wat; N = N3_; tI = bid - XBLK; }
    else                    { w = wp; wt = wpt; N = C_;  tI = bid - XBLK - WABLK; }
    const int ntn = N / 32;
    const int n0 = (tI % ntn) * 32, k0 = (tI / ntn) * 32;
    const int tx = t & 31, ty = t >> 5;        // 32 x 8
    for (int i = ty; i < 32; i += 8) tile[i][tx] = w[(size_t)(k0 + i) * N + n0 + tx];
    __syncthreads();
    for (int i = ty; i < 32; i += 8)
        wt[(size_t)(n0 + i) * C_ + k0 + tx] = __float2bfloat16(tile[tx][i]);
}

// ---------- double-buffered MFMA GEMM core: BM=128, BN=192, BK=64 ----------
// 256 threads = 4 waves (2 row x 2 col), wave tile 64x96. LDS 80 KB
// (A 2x16K + B 2x24K) -> 2 blocks/CU resident; blocks are barrier-independent
// so one block's sync/stage overlaps the other's MFMA (cross-block TLP).
// ONE __syncthreads per K-tile ("minimum 2-phase" T3 recipe): issue
// stage(t+1) FIRST, then ds_read+MFMA of tile t (compiler interleaves with
// counted lgkmcnt), then sync (drains vmcnt+lgkm, flips buffers).

template<bool SWAPPED>
__device__ __forceinline__ void gemm_db_core(
        const bf16* __restrict__ Ap, const bf16* __restrict__ Bp,
        const int m0, const int n0, bf16* smem, facc (&acc)[4][6]) {
    constexpr int KD = 768, NT = 12;
    bf16* As = smem;                  // [2][128*64]
    bf16* Bs = smem + 2 * 8192;       // [2][192*64]
    const int t = threadIdx.x, w = t >> 6, lane = t & 63;
    const int wrow = (w >> 1) * 64;                  // 2 row-waves
    const int wcol = (w & 1) * 96;                   // 2 col-waves
    const int fr = lane & 15, quad = lane >> 4;
    const int pc0 = (quad ^ (fr & 7)) * 8;           // swizzled read chunk, kk=0
    const int pc1 = ((quad + 4) ^ (fr & 7)) * 8;     // kk=1
    const int srow = t >> 3;                         // 0..31 staging row
    const int schunk = ((t & 7) ^ (srow & 7)) * 8;   // swizzled source chunk
    const int sdo = t * 8;                           // linear LDS dest

    const bf16* Ag = Ap + (size_t)(m0 + srow) * KD + schunk;
    const bf16* Bg = Bp + (size_t)(n0 + srow) * KD + schunk;

#pragma unroll
    for (int i = 0; i < 4; ++i)
#pragma unroll
        for (int c = 0; c < 6; ++c)
#pragma unroll
            for (int r = 0; r < 4; ++r) acc[i][c][r] = 0.f;

    auto stageA = [&](bf16* dst, int k0) {           // 4 passes of 32 rows
        const bf16* s = Ag + k0;
        bf16* d = dst + sdo;
#pragma unroll
        for (int r = 0; r < 4; ++r)
            gload_lds16(s + (size_t)(r * 32) * KD, d + r * 2048);
    };
    auto stageB = [&](bf16* dst, int k0) {           // 6 passes of 32 rows
        const bf16* s = Bg + k0;
        bf16* d = dst + sdo;
#pragma unroll
        for (int r = 0; r < 6; ++r)
            gload_lds16(s + (size_t)(r * 32) * KD, d + r * 2048);
    };

    // prologue: stage tile 0
    stageA(As, 0);
    stageB(Bs, 0);
    __syncthreads();

#pragma unroll 2
    for (int kt = 0; kt < NT; ++kt) {
        const int cb = kt & 1;
        const bf16* AsC = As + cb * 8192;
        const bf16* BsC = Bs + cb * 12288;
        // issue next-tile staging FIRST so gloads overlap this tile's compute
        if (kt + 1 < NT) {
            stageA(As + (cb ^ 1) * 8192,  (kt + 1) * 64);
            stageB(Bs + (cb ^ 1) * 12288, (kt + 1) * 64);
        }
        bfrag af[4][2];
#pragma unroll
        for (int i = 0; i < 4; ++i) {
            const bf16* ar = AsC + (wrow + i * 16 + fr) * 64;
            af[i][0] = *(const bfrag*)(ar + pc0);
            af[i][1] = *(const bfrag*)(ar + pc1);
        }
#pragma unroll
        for (int c = 0; c < 6; ++c) {
            const bf16* br = BsC + (wcol + c * 16 + fr) * 64;
            bfrag b0 = *(const bfrag*)(br + pc0);
            bfrag b1 = *(const bfrag*)(br + pc1);
#pragma unroll
            for (int i = 0; i < 4; ++i) {
                if constexpr (SWAPPED) {
                    acc[i][c] = __builtin_amdgcn_mfma_f32_16x16x32_bf16(b0, af[i][0], acc[i][c], 0, 0, 0);
                    acc[i][c] = __builtin_amdgcn_mfma_f32_16x16x32_bf16(b1, af[i][1], acc[i][c], 0, 0, 0);
                } else {
                    acc[i][c] = __builtin_amdgcn_mfma_f32_16x16x32_bf16(af[i][0], b0, acc[i][c], 0, 0, 0);
                    acc[i][c] = __builtin_amdgcn_mfma_f32_16x16x32_bf16(af[i][1], b1, acc[i][c], 0, 0, 0);
                }
            }
        }
        __syncthreads();   // drains vmcnt(0)+lgkmcnt(0); buffer flip
    }
}

// qkv: A=xb [8192x768], Bt=WaT [2304x768] -> Q,K [B,H,T,64] bf16 (swapped, packed),
// V transposed Vt [B,H,64,T] (non-swapped). Grid 768 blocks, 2 blocks/CU.
__global__ __launch_bounds__(256, 2) void qkv_db_kernel(
        const bf16* __restrict__ xb, const bf16* __restrict__ wat,
        const float* __restrict__ bias,
        bf16* __restrict__ Q, bf16* __restrict__ K, bf16* __restrict__ Vt) {
    extern __shared__ bf16 smem[];
    const int id = blockIdx.x;
    const int wg = (id & 7) * 96 + (id >> 3);      // bijective XCD swizzle (768%8==0)
    const int bx = wg % 12, by = wg / 12;
    const int m0 = by * 128, n0 = bx * 192;
    const int which = n0 / C_;                     // block-uniform: 0=Q 1=K 2=V

    facc acc[4][6];
    if (which < 2) gemm_db_core<true >(xb, wat, m0, n0, smem, acc);
    else           gemm_db_core<false>(xb, wat, m0, n0, smem, acc);

    const int t = threadIdx.x, w = t >> 6, lane = t & 63;
    const int wr = (w >> 1) * 64, wc = (w & 1) * 96;
    const int fr = lane & 15, quad = lane >> 4;
    const int bb = m0 >> 10;                       // uniform batch index
    if (which < 2) {
        bf16* dst = which ? K : Q;
        const float sc = which ? 1.0f : QSCALE_;
#pragma unroll
        for (int i = 0; i < 4; ++i) {
            const int tt = (m0 & 1023) + wr + i * 16 + fr;     // token (lane-major)
#pragma unroll
            for (int c = 0; c < 6; ++c) {
                const int colbase = n0 + wc + c * 16 + quad * 4;
                const int cc = colbase - which * C_;
                const int h = cc >> 6, d0 = cc & 63;
                const float4 bv = *(const float4*)(bias + colbase);
                short4v pk;
                pk[0] = bfbits((acc[i][c][0] + bv.x) * sc);
                pk[1] = bfbits((acc[i][c][1] + bv.y) * sc);
                pk[2] = bfbits((acc[i][c][2] + bv.z) * sc);
                pk[3] = bfbits((acc[i][c][3] + bv.w) * sc);
                *(short4v*)(dst + ((size_t)(bb * H_ + h) * T_ + tt) * HD_ + d0) = pk;
            }
        }
    } else {
#pragma unroll
        for (int i = 0; i < 4; ++i) {
            const int tt0 = (m0 & 1023) + wr + i * 16 + quad * 4;  // token, +r over pack
#pragma unroll
            for (int c = 0; c < 6; ++c) {
                const int col = n0 + wc + c * 16 + fr;
                const int cc = col - 2 * C_;
                const int h = cc >> 6, d = cc & 63;
                const float bv = bias[col];
                short4v pk;
                pk[0] = bfbits(acc[i][c][0] + bv);
                pk[1] = bfbits(acc[i][c][1] + bv);
                pk[2] = bfbits(acc[i][c][2] + bv);
                pk[3] = bfbits(acc[i][c][3] + bv);
                *(short4v*)(Vt + ((size_t)(bb * H_ + h) * HD_ + d) * T_ + tt0) = pk;
            }
        }
    }
}

// proj: A=Y [8192x768] bf16, Bt=WpT [768x768] -> fp32 out + bias (swapped).
// Grid 256 blocks = 1/CU.
__global__ __launch_bounds__(256, 2) void proj_db_kernel(
        const bf16* __restrict__ y, const bf16* __restrict__ wpt,
        const float* __restrict__ bias, float* __restrict__ out) {
    extern __shared__ bf16 smem[];
    const int id = blockIdx.x;
    const int wg = (id & 7) * 32 + (id >> 3);      // bijective XCD swizzle (256%8==0)
    const int bx = wg % 4, by = wg / 4;
    const int m0 = by * 128, n0 = bx * 192;

    facc acc[4][6];
    gemm_db_core<true>(y, wpt, m0, n0, smem, acc);

    const int t = threadIdx.x, w = t >> 6, lane = t & 63;
    const int wr = (w >> 1) * 64, wc = (w & 1) * 96;
    const int fr = lane & 15, quad = lane >> 4;
#pragma unroll
    for (int i = 0; i < 4; ++i) {
        const int row = m0 + wr + i * 16 + fr;
#pragma unroll
        for (int c = 0; c < 6; ++c) {
            const int colbase = n0 + wc + c * 16 + quad * 4;
            const float4 bv = *(const float4*)(bias + colbase);
            float4 v;
            v.x = acc[i][c][0] + bv.x;
            v.y = acc[i][c][1] + bv.y;
            v.z = acc[i][c][2] + bv.z;
            v.w = acc[i][c][3] + bv.w;
            *(float4*)(out + (size_t)row * C_ + colbase) = v;
        }
    }
}

// ---------- flash attention: exp2 static-max softmax + 2 K-tiles per barrier ----------
__global__ __launch_bounds__(256) void flash_attn_kernel(
        const bf16* __restrict__ Q, const bf16* __restrict__ K,
        const bf16* __restrict__ Vt, bf16* __restrict__ Y) {
    const int id   = blockIdx.x;
    const int bh   = (id & 7) * 12 + ((id >> 3) % 12);    // XCD affinity
    const int qpair = (id >> 3) / 12;                     // 0..7
    const int t = threadIdx.x, w = t >> 6, lane = t & 63;
    const int fr = lane & 15, quad = lane >> 4, fq = quad * 8;

    __shared__ bf16 sK[2][64 * 64];       // [buf][key][dim], chunk-swizzled
    __shared__ bf16 sVt[2][64 * 64];      // [buf][dim][key], chunk-swizzled
    __shared__ bf16 sP[4][16][72];        // wave-private P, row stride 72 (16B aligned)

    const bf16* Kbh = K  + (size_t)bh * T_ * HD_;
    const bf16* Vbh = Vt + (size_t)bh * HD_ * T_;
    const int b_ = bh / H_, h_ = bh % H_;

    const int srow = t >> 3;                                // 0..31 (staging row)
    const int sgc  = ((t & 7) ^ (srow & 7)) * 8;            // swizzled source chunk
    const int c0   = (quad ^ (fr & 7)) * 8;                 // swizzled read chunk

    for (int phase = 0; phase < 2; ++phase) {
        const int qt = (phase == 0) ? (15 - qpair) : qpair; // heavy tile first
        const int q0 = qt * 64;

        const bf16* qbase = Q + ((size_t)bh * T_ + q0 + w * 16 + fr) * HD_;
        bfrag qa0 = *(const bfrag*)(qbase + fq);
        bfrag qa1 = *(const bfrag*)(qbase + 32 + fq);

        facc o[4];
        for (int nb = 0; nb < 4; ++nb) for (int r = 0; r < 4; ++r) o[nb][r] = 0.f;
        float rowl[4] = {0.f, 0.f, 0.f, 0.f};

        auto tile_step = [&](int kt, const bf16* sKp, const bf16* sVp) {
            const int k0 = kt * 64;
            facc s[4];
            for (int nb = 0; nb < 4; ++nb) for (int r = 0; r < 4; ++r) s[nb][r] = 0.f;
            for (int nb = 0; nb < 4; ++nb) {
                const bf16* kr = sKp + (nb * 16 + fr) * 64;
                bfrag kb0 = *(const bfrag*)(kr + c0);
                bfrag kb1 = *(const bfrag*)(kr + (c0 ^ 32));
                s[nb] = __builtin_amdgcn_mfma_f32_16x16x32_bf16(qa0, kb0, s[nb], 0, 0, 0);
                s[nb] = __builtin_amdgcn_mfma_f32_16x16x32_bf16(qa1, kb1, s[nb], 0, 0, 0);
            }
            const int mrow0 = q0 + w * 16 + quad * 4;   // + r
            float p[4][4];
            if (kt == qt) {
                for (int nb = 0; nb < 4; ++nb) {
                    const int n_g = k0 + nb * 16 + fr;
                    for (int r = 0; r < 4; ++r) {
                        const float a = (n_g > mrow0 + r) ? -1e30f : s[nb][r] - M2_;
                        p[nb][r] = fexp2(a);
                    }
                }
            } else {
                for (int nb = 0; nb < 4; ++nb)
                    for (int r = 0; r < 4; ++r)
                        p[nb][r] = fexp2(s[nb][r] - M2_);
            }
            for (int r = 0; r < 4; ++r)
                rowl[r] += p[0][r] + p[1][r] + p[2][r] + p[3][r];
            for (int nb = 0; nb < 4; ++nb)
                for (int r = 0; r < 4; ++r)
                    sP[w][quad * 4 + r][nb * 16 + fr] = __float2bfloat16(p[nb][r]);
            bfrag pa0 = *(const bfrag*)(&sP[w][fr][fq]);
            bfrag pa1 = *(const bfrag*)(&sP[w][fr][32 + fq]);
            for (int nb = 0; nb < 4; ++nb) {
                const bf16* vr = sVp + (nb * 16 + fr) * 64;
                bfrag vb0 = *(const bfrag*)(vr + c0);
                bfrag vb1 = *(const bfrag*)(vr + (c0 ^ 32));
                o[nb] = __builtin_amdgcn_mfma_f32_16x16x32_bf16(pa0, vb0, o[nb], 0, 0, 0);
                o[nb] = __builtin_amdgcn_mfma_f32_16x16x32_bf16(pa1, vb1, o[nb], 0, 0, 0);
            }
        };

        for (int kt = 0; kt <= qt; kt += 2) {
            const int k0 = kt * 64;
            const bool two = (kt + 1 <= qt);
            gload_lds16(Kbh + (size_t)(k0 + srow) * HD_ + sgc,      sK[0] + t * 8);
            gload_lds16(Kbh + (size_t)(k0 + 32 + srow) * HD_ + sgc, sK[0] + 2048 + t * 8);
            gload_lds16(Vbh + (size_t)srow * T_ + k0 + sgc,         sVt[0] + t * 8);
            gload_lds16(Vbh + (size_t)(srow + 32) * T_ + k0 + sgc,  sVt[0] + 2048 + t * 8);
            if (two) {
                const int k1 = k0 + 64;
                gload_lds16(Kbh + (size_t)(k1 + srow) * HD_ + sgc,      sK[1] + t * 8);
                gload_lds16(Kbh + (size_t)(k1 + 32 + srow) * HD_ + sgc, sK[1] + 2048 + t * 8);
                gload_lds16(Vbh + (size_t)srow * T_ + k1 + sgc,         sVt[1] + t * 8);
                gload_lds16(Vbh + (size_t)(srow + 32) * T_ + k1 + sgc,  sVt[1] + 2048 + t * 8);
            }
            __syncthreads();
            tile_step(kt, sK[0], sVt[0]);
            if (two) tile_step(kt + 1, sK[1], sVt[1]);
            __syncthreads();
        }

        for (int r = 0; r < 4; ++r) {
            float l = rowl[r];
            l += __shfl_xor(l, 1);
            l += __shfl_xor(l, 2);
            l += __shfl_xor(l, 4);
            l += __shfl_xor(l, 8);
            const float inv = 1.0f / l;
            const int tt = q0 + w * 16 + quad * 4 + r;
            bf16* yrow = Y + ((size_t)b_ * T_ + tt) * C_ + h_ * HD_;
            for (int nb = 0; nb < 4; ++nb)
                yrow[nb * 16 + fr] = __float2bfloat16(o[nb][r] * inv);
        }
    }
}

extern "C" void kernel_launch(void* const* d_in, const int* in_sizes, int n_in,
                              void* d_out, int out_size, void* d_ws, size_t ws_size,
                              hipStream_t stream) {
    const float* x      = (const float*)d_in[0];
    const float* W_attn = (const float*)d_in[1];
    const float* b_attn = (const float*)d_in[2];
    const float* W_proj = (const float*)d_in[3];
    const float* b_proj = (const float*)d_in[4];
    float* out = (float*)d_out;

    const size_t per = (size_t)B_ * H_ * T_ * HD_;   // 6291456 bf16
    bf16* Q   = (bf16*)d_ws;
    bf16* K   = Q + per;
    bf16* Vt  = K + per;                 // transposed V [B,H,64,T]
    bf16* XbY = Vt + per;                // x-bf16, later attention output Y
    bf16* WaT = XbY + per;
    bf16* WpT = WaT + (size_t)N3_ * C_;

    static bool s_attr = false;
    if (!s_attr) {
        hipFuncSetAttribute((const void*)qkv_db_kernel,
                            hipFuncAttributeMaxDynamicSharedMemorySize, 81920);
        hipFuncSetAttribute((const void*)proj_db_kernel,
                            hipFuncAttributeMaxDynamicSharedMemorySize, 81920);
        s_attr = true;
    }

    cvt_all_kernel<<<dim3(XBLK + WABLK + 576), dim3(256), 0, stream>>>(
        x, XbY, W_attn, WaT, W_proj, WpT);
    qkv_db_kernel<<<dim3(768), dim3(256), 81920, stream>>>(
        XbY, WaT, b_attn, Q, K, Vt);
    flash_attn_kernel<<<dim3(768), dim3(256), 0, stream>>>(Q, K, Vt, XbY);
    proj_db_kernel<<<dim3(256), dim3(256), 81920, stream>>>(
        XbY, WpT, b_proj, out);
}